// Round 4
// baseline (190.002 us; speedup 1.0000x reference)
//
#include <hip/hip_runtime.h>
#include <math.h>

#define HOP       128
#define NBINS     257
#define NFRAMES   4000
#define NB        16
#define OUT_LEN   512383          // (4000-1)*128 + 512 - 1
#define CPR       16              // chunks per range (per wave)
#define RPB       251             // ranges per batch = ceil(4003/16)
#define NCHUNK    4003            // output chunks of 128 (last has 127 samples)
#define NPAIRS    10              // frame-pairs per wave = (CPR+4)/2
#define PBF4      320             // per-wave LDS scratch (float4) per buffer

__device__ __forceinline__ float2 cmul(float2 a, float2 b) {
    return make_float2(a.x*b.x - a.y*b.y, a.x*b.y + a.y*b.x);
}

// Inverse-sign DFT4: y[t] = sum_j x[j] * i^(j*t)
__device__ __forceinline__ void dft4(const float2* x, float2* y) {
    const float s0r=x[0].x+x[2].x, s0i=x[0].y+x[2].y;
    const float d0r=x[0].x-x[2].x, d0i=x[0].y-x[2].y;
    const float s1r=x[1].x+x[3].x, s1i=x[1].y+x[3].y;
    const float d1r=x[1].x-x[3].x, d1i=x[1].y-x[3].y;
    y[0]=make_float2(s0r+s1r, s0i+s1i);
    y[2]=make_float2(s0r-s1r, s0i-s1i);
    y[1]=make_float2(d0r-d1i, d0i+d1r);   // d0 + i*d1
    y[3]=make_float2(d0r+d1i, d0i-d1r);   // d0 - i*d1
}

// Real-packed iSTFT, 2-frame-paired: each FFT pass computes TWO frames'
// packed 256-pt inverse FFTs, frame pair interleaved as .xy/.zw of float4
// LDS slots (b128 transposes). Latency-bound on 3 dependent LDS
// round-trips/pass; pairing amortizes them over 2 frames.
//
// LAUNCH-BOUNDS LEDGER (hard-won, do not regress):
//   (256,8) -> cap 32 VGPR  -> catastrophic spill (293 us, r1)
//   (256,4) -> cap 64 VGPR  -> spill: FETCH 281 MB, VALUBusy 17.5%, 160 us (r2)
//   (256,2) -> cap 128, allocator uses 88, zero spill, 72.4 us (r3)
//   empirical mapping on this toolchain: cap = 256 / min_waves_per_EU.
//
// CPR LEDGER:
//   CPR=8  (r3): 8016 waves = 2 residency fills at the 16-waves/CU cap
//                (88 VGPR -> 4 waves/SIMD), avg occupancy 18%; halo = 12
//                frame-FFTs per 8 chunks (1.5x ideal).  72.4 us.
//   CPR=16 (r4): 4016 waves <= 4096 resident -> single fill; halo 20/16
//                (1.25x) -> 17% less FFT work.
__global__ __launch_bounds__(256, 2)
void istft_pk4_kernel(const float* __restrict__ re,
                      const float* __restrict__ im,
                      float* __restrict__ out)
{
    __shared__ float4 bufA[4][PBF4];   // 4 waves * 320 * 16 B = 20480 B
    __shared__ float4 bufB[4][PBF4];   // total 40960 B / block

    const int tid = threadIdx.x;
    const int wv  = tid >> 6;
    const int l   = tid & 63;
    float4* PA = bufA[wv];
    float4* PBp = bufB[wv];

    const int rid = blockIdx.x * 4 + wv;     // 0..4015 exact
    const int b   = rid / RPB;
    const int rr  = rid - b * RPB;
    const int c0  = rr * CPR;
    const int fend = min(c0 + CPR - 1, NCHUNK - 1);

    const float* __restrict__ reb = re + (size_t)b * NFRAMES * NBINS;
    const float* __restrict__ imb = im + (size_t)b * NFRAMES * NBINS;
    float* __restrict__ outb = out + (size_t)b * OUT_LEN;

    // ---- frame-invariant per-lane constants (shared by both frames of a pair) ----
    const float TWO_PI = 6.2831853071795864f;
    const float RQ = 0.70710678118654752f;
    // Pack twiddle seed e^{2 pi i l/512}; +64-bin step = pi/4 rotation,
    // walked inside stage1 (keeps only 2 persistent regs).
    float2 ctw0;
    { float s, c; __sincosf(TWO_PI * (float)l * (1.0f/512.0f), &s, &c);
      ctw0 = make_float2(c, s); }
    float2 w1, w2, w3;
    { float s, c; __sincosf(TWO_PI * (float)l * (1.0f/256.0f), &s, &c);
      w1 = make_float2(c, s); w2 = cmul(w1, w1); w3 = cmul(w2, w1); }
    float2 b1, b2, b3;
    { float s, c; __sincosf(TWO_PI * (float)(l & 15) * (1.0f/64.0f), &s, &c);
      b1 = make_float2(c, s); b2 = cmul(b1, b1); b3 = cmul(b2, b1); }
    float2 q1, q2, q3;
    { float s, c; __sincosf(TWO_PI * (float)(l & 3) * (1.0f/16.0f), &s, &c);
      q1 = make_float2(c, s); q2 = cmul(q1, q1); q3 = cmul(q2, q1); }
    // Window weights for samples 2l+128o (x) / 2l+1+128o (y); Hann identity
    // ww[2]=2S-ww[0], ww[3]=2S-ww[1] keeps only o=0,1 persistent.
    const float S2 = 1.3020833333e-3f;    // 2 * 0.5/768
    float wwx0, wwx1, wwy0, wwy1;
    {
        const float S = 6.5104166667e-4f;   // 0.5/768
        float sx, cx; __sincosf(TWO_PI * (float)(2*l) * (1.0f/512.0f), &sx, &cx);
        wwx0 = S*(1.0f-cx); wwx1 = S*(1.0f+sx);
        float sy, cy; __sincosf(TWO_PI * (float)(2*l+1) * (1.0f/512.0f), &sy, &cy);
        wwy0 = S*(1.0f-cy); wwy1 = S*(1.0f+sy);
    }
    // Transpose layouts (float4 index; same index algebra as the proven
    // conflict-free b64 version).  r2/r3 measured ~3M bank-conflict cycles
    // (~7% of CU-cycles) on the stride-20 patterns -- known, minor; candidate
    // for a later round, not this one.
    const int a1w = l;                                        // + 64*t0
    const int a1r = (l & 15) + 64 * (l >> 4);                 // + 16*q
    const int a2w = (l & 15) + 20 * (l >> 4);                 // + 80*t1
    const int a2r = (l & 3) + 20 * ((l >> 2) & 3) + 80 * (l >> 4);   // + 4*r
    const int a3w = ((l >> 2) & 3) + 4 * (l >> 4) + 20 * (l & 3);    // + 80*t2
    const int a3r = (l & 3) + 4 * ((l >> 2) & 3) + 80 * (l >> 4);    // + 20*k0

    float accx[4], accy[4];
    #pragma unroll
    for (int o = 0; o < 4; ++o) { accx[o] = 0.0f; accy[o] = 0.0f; }

    // Raw prefetch registers for the next PAIR of frames.
    float dra[4], dia[4], mra[4], mia[4];
    float drb[4], dib[4], mrb[4], mib[4];

    auto issue_loads = [&](int fq) {           // frames fq (a) and fq+1 (b)
        const int fca = min(max(fq,     0), NFRAMES - 1);
        const int fcb = min(max(fq + 1, 0), NFRAMES - 1);
        const float* __restrict__ rba = reb + (size_t)fca * NBINS;
        const float* __restrict__ iba = imb + (size_t)fca * NBINS;
        const float* __restrict__ rbb = reb + (size_t)fcb * NBINS;
        const float* __restrict__ ibb = imb + (size_t)fcb * NBINS;
        #pragma unroll
        for (int j = 0; j < 4; ++j) {
            const int k = l + 64*j, km = 256 - k;
            dra[j] = rba[k];  dia[j] = iba[k];
            mra[j] = rba[km]; mia[j] = iba[km];
            drb[j] = rbb[k];  dib[j] = ibb[k];
            mrb[j] = rbb[km]; mib[j] = ibb[km];
        }
    };

    // Stage-1 math for one frame: pack + dft4 + w-twiddles -> A[4].
    auto s1frame = [&](const float* dr_, const float* di_,
                       const float* mr_, const float* mi_, float2* A) {
        float2 Cv[4];
        float cc = ctw0.x, ss = ctw0.y;   // walking twiddle, pi/4 per j-step
        #pragma unroll
        for (int j = 0; j < 4; ++j) {
            float ydr = dr_[j], ydi = di_[j], ymr = mr_[j], ymi = mi_[j];
            if (j == 0) {                       // k==0: Im of DC & Nyquist ignored
                const bool z = (l == 0);
                ydi = z ? 0.0f : ydi;
                ymi = z ? 0.0f : ymi;
            }
            const float er  = ydr + ymr, ei  = ydi - ymi;
            const float fr2 = ydr - ymr, fi2 = ydi + ymi;
            const float gr = cc*fr2 - ss*fi2;
            const float gi = cc*fi2 + ss*fr2;
            Cv[j] = make_float2(er - gi, ei + gr);
            const float cn = (cc - ss) * RQ, sn = (ss + cc) * RQ;  // rotate pi/4
            cc = cn; ss = sn;
        }
        dft4(Cv, A);
        A[1] = cmul(A[1], w1); A[2] = cmul(A[2], w2); A[3] = cmul(A[3], w3);
    };

    auto stage1 = [&](float4* __restrict__ P) {
        float2 Aa[4], Ab[4];
        s1frame(dra, dia, mra, mia, Aa);
        s1frame(drb, dib, mrb, mib, Ab);
        #pragma unroll
        for (int j = 0; j < 4; ++j)
            P[a1w + 64*j] = make_float4(Aa[j].x, Aa[j].y, Ab[j].x, Ab[j].y);
    };

    auto stages234 = [&](float4* __restrict__ P, int fa) {
        float2 Ga[4], Gb[4], Aa[4], Ab[4];
        // ---- stage 2 ----
        #pragma unroll
        for (int t = 0; t < 4; ++t) {
            const float4 g = P[a1r + 16*t];
            Ga[t] = make_float2(g.x, g.y); Gb[t] = make_float2(g.z, g.w);
        }
        dft4(Ga, Aa); dft4(Gb, Ab);
        Aa[1]=cmul(Aa[1],b1); Aa[2]=cmul(Aa[2],b2); Aa[3]=cmul(Aa[3],b3);
        Ab[1]=cmul(Ab[1],b1); Ab[2]=cmul(Ab[2],b2); Ab[3]=cmul(Ab[3],b3);
        #pragma unroll
        for (int t = 0; t < 4; ++t)
            P[a2w + 80*t] = make_float4(Aa[t].x, Aa[t].y, Ab[t].x, Ab[t].y);
        // ---- stage 3 ----
        #pragma unroll
        for (int t = 0; t < 4; ++t) {
            const float4 g = P[a2r + 4*t];
            Ga[t] = make_float2(g.x, g.y); Gb[t] = make_float2(g.z, g.w);
        }
        dft4(Ga, Aa); dft4(Gb, Ab);
        Aa[1]=cmul(Aa[1],q1); Aa[2]=cmul(Aa[2],q2); Aa[3]=cmul(Aa[3],q3);
        Ab[1]=cmul(Ab[1],q1); Ab[2]=cmul(Ab[2],q2); Ab[3]=cmul(Ab[3],q3);
        #pragma unroll
        for (int t = 0; t < 4; ++t)
            P[a3w + 80*t] = make_float4(Aa[t].x, Aa[t].y, Ab[t].x, Ab[t].y);
        // ---- stage 4 ----
        #pragma unroll
        for (int t = 0; t < 4; ++t) {
            const float4 g = P[a3r + 20*t];
            Ga[t] = make_float2(g.x, g.y); Gb[t] = make_float2(g.z, g.w);
        }
        dft4(Ga, Aa); dft4(Gb, Ab);
        // ---- OLA: frame fa first (chunk fa must NOT see frame fb), then fb ----
        const int fb = fa + 1;
        if (fa >= 0 && fa < NFRAMES) {          // wave-uniform gate
            accx[0] = fmaf(Aa[0].x, wwx0, accx[0]);
            accx[1] = fmaf(Aa[1].x, wwx1, accx[1]);
            accx[2] = fmaf(Aa[2].x, S2, fmaf(-Aa[2].x, wwx0, accx[2]));
            accx[3] = fmaf(Aa[3].x, S2, fmaf(-Aa[3].x, wwx1, accx[3]));
            accy[0] = fmaf(Aa[0].y, wwy0, accy[0]);
            accy[1] = fmaf(Aa[1].y, wwy1, accy[1]);
            accy[2] = fmaf(Aa[2].y, S2, fmaf(-Aa[2].y, wwy0, accy[2]));
            accy[3] = fmaf(Aa[3].y, S2, fmaf(-Aa[3].y, wwy1, accy[3]));
        }
        if (fa >= c0 && fa <= fend) {           // emit chunk fa (complete now)
            const int s0 = fa * HOP + 2*l;      // max 512382 < OUT_LEN
            outb[s0] = accx[0];
            const int s1 = s0 + 1;
            if (s1 < OUT_LEN) outb[s1] = accy[0];
        }
        #pragma unroll
        for (int o = 0; o < 3; ++o) { accx[o] = accx[o+1]; accy[o] = accy[o+1]; }
        accx[3] = 0.0f; accy[3] = 0.0f;
        if (fb >= 0 && fb < NFRAMES) {
            accx[0] = fmaf(Ab[0].x, wwx0, accx[0]);
            accx[1] = fmaf(Ab[1].x, wwx1, accx[1]);
            accx[2] = fmaf(Ab[2].x, S2, fmaf(-Ab[2].x, wwx0, accx[2]));
            accx[3] = fmaf(Ab[3].x, S2, fmaf(-Ab[3].x, wwx1, accx[3]));
            accy[0] = fmaf(Ab[0].y, wwy0, accy[0]);
            accy[1] = fmaf(Ab[1].y, wwy1, accy[1]);
            accy[2] = fmaf(Ab[2].y, S2, fmaf(-Ab[2].y, wwy0, accy[2]));
            accy[3] = fmaf(Ab[3].y, S2, fmaf(-Ab[3].y, wwy1, accy[3]));
        }
        if (fb >= c0 && fb <= fend) {
            const int s0 = fb * HOP + 2*l;
            outb[s0] = accx[0];
            const int s1 = s0 + 1;
            if (s1 < OUT_LEN) outb[s1] = accy[0];
        }
        #pragma unroll
        for (int o = 0; o < 3; ++o) { accx[o] = accx[o+1]; accy[o] = accy[o+1]; }
        accx[3] = 0.0f; accy[3] = 0.0f;
    };

    // ---- software-pipelined pair loop: NPAIRS pairs = frames c0-4 .. c0+CPR-1 ----
    // (frame c0-4 contributes only to chunks < c0: harmless 1-frame halo waste;
    //  frames > fend are load-clamped + acc/emit-gated.)
    const int base = c0 - 4;
    issue_loads(base);
    stage1(PA);
    #pragma unroll 1
    for (int p = 0; p < NPAIRS; p += 2) {
        issue_loads(base + 2*(p+1));   // in flight during stages234(pair p)
        stages234(PA, base + 2*p);
        stage1(PBp);                   // consumes pair p+1 loads
        if (p + 2 < NPAIRS) issue_loads(base + 2*(p+2));
        stages234(PBp, base + 2*(p+1));
        if (p + 2 < NPAIRS) stage1(PA);
    }
}

extern "C" void kernel_launch(void* const* d_in, const int* in_sizes, int n_in,
                              void* d_out, int out_size, void* d_ws, size_t ws_size,
                              hipStream_t stream) {
    (void)in_sizes; (void)n_in; (void)d_ws; (void)ws_size; (void)out_size;
    const float* re = (const float*)d_in[0];
    const float* im = (const float*)d_in[1];
    float* out = (float*)d_out;

    // 16 batches x 251 ranges = 4016 waves; 4 waves per 256-thread block.
    // 1004 blocks at 4 blocks/CU (LDS cap) -> whole grid co-resident, one fill.
    const int nblocks = (NB * RPB) / 4;   // 1004
    istft_pk4_kernel<<<dim3(nblocks), dim3(256), 0, stream>>>(re, im, out);
}

// Round 5
// 183.974 us; speedup vs baseline: 1.0328x; 1.0328x over previous
//
#include <hip/hip_runtime.h>
#include <math.h>

#define HOP       128
#define NBINS     257
#define NFRAMES   4000
#define NB        16
#define OUT_LEN   512383          // (4000-1)*128 + 512 - 1
#define CPR       12              // chunks per range (per wave)
#define RPB       334             // ranges per batch = ceil(4003/12)
#define NCHUNK    4003            // output chunks of 128 (last has 127 samples)
#define NPAIRS    8               // frame-pairs per wave = (CPR+4)/2
#define PBF4      320             // per-wave LDS scratch (float4) per buffer

__device__ __forceinline__ float2 cmul(float2 a, float2 b) {
    return make_float2(a.x*b.x - a.y*b.y, a.x*b.y + a.y*b.x);
}

// Inverse-sign DFT4: y[t] = sum_j x[j] * i^(j*t)
__device__ __forceinline__ void dft4(const float2* x, float2* y) {
    const float s0r=x[0].x+x[2].x, s0i=x[0].y+x[2].y;
    const float d0r=x[0].x-x[2].x, d0i=x[0].y-x[2].y;
    const float s1r=x[1].x+x[3].x, s1i=x[1].y+x[3].y;
    const float d1r=x[1].x-x[3].x, d1i=x[1].y-x[3].y;
    y[0]=make_float2(s0r+s1r, s0i+s1i);
    y[2]=make_float2(s0r-s1r, s0i-s1i);
    y[1]=make_float2(d0r-d1i, d0i+d1r);   // d0 + i*d1
    y[3]=make_float2(d0r+d1i, d0i-d1r);   // d0 - i*d1
}

// Real-packed iSTFT, 2-frame-paired: each FFT pass computes TWO frames'
// packed 256-pt inverse FFTs, frame pair interleaved as .xy/.zw of float4
// LDS slots (b128 transposes). Latency-bound on 3 dependent LDS
// round-trips/pass; pairing amortizes them over 2 frames.
//
// OCCUPANCY MODEL (validated against r0-r4 measured OccupancyPercent):
//   waves/EU = floor(256 / VGPR_Count)   [effective 256-reg pool per SIMD]
//     r1: 32 VGPR -> 8/EU (occ 84%)   r2: 64 -> 4/EU (42%)
//     r3/r4: 88 -> 2/EU (18%)         r0: 68 -> 3/EU (27%)
//   and the launch_bounds 2nd arg N caps the allocator at 256/N VGPRs:
//     (256,8)->32  (256,4)->64  (256,2)->128(used 88)
//   r2/r1 proved: forcing below the kernel's ~76-88 live regs = spill
//   catastrophe (FETCH 281-710 MB).  This round: trim 12 persistent regs
//   (w2,w3,b2,b3,q2,q3 -> per-pair transients) to fit the 85-reg band,
//   (256,3) -> 3 waves/EU, +50% latency hiding at zero spill.
//
// CPR LEDGER:
//   CPR=8  (r3): 72.4 us @ 2 waves/EU, halo 1.5x, fill util 98%
//   CPR=16 (r4): 76 us -- 2 ragged fills at cap 8/CU (util 65%), regression
//   CPR=12 (r5): 5344 waves, 1336 blocks = 5.22/CU over 3-resident
//                -> 2 rounds, util 87%, halo 1.33x
__global__ __launch_bounds__(256, 3)
void istft_pk4_kernel(const float* __restrict__ re,
                      const float* __restrict__ im,
                      float* __restrict__ out)
{
    __shared__ float4 bufA[4][PBF4];   // 4 waves * 320 * 16 B = 20480 B
    __shared__ float4 bufB[4][PBF4];   // total 40960 B / block
    // LDS at 3 blocks/CU = 122880 B <= 163840 -- not binding.

    const int tid = threadIdx.x;
    const int wv  = tid >> 6;
    const int l   = tid & 63;
    float4* PA = bufA[wv];
    float4* PBp = bufB[wv];

    const int rid = blockIdx.x * 4 + wv;     // 0..5343 exact
    const int b   = rid / RPB;
    const int rr  = rid - b * RPB;
    const int c0  = rr * CPR;
    const int fend = min(c0 + CPR - 1, NCHUNK - 1);

    const float* __restrict__ reb = re + (size_t)b * NFRAMES * NBINS;
    const float* __restrict__ imb = im + (size_t)b * NFRAMES * NBINS;
    float* __restrict__ outb = out + (size_t)b * OUT_LEN;

    // ---- frame-invariant per-lane constants (persistent set kept minimal:
    //      ctw0, w1, b1, q1, ww*4 = 12 regs; squares/cubes are per-pair
    //      transients to stay under the 85-VGPR / 3-waves-per-EU line) ----
    const float TWO_PI = 6.2831853071795864f;
    const float RQ = 0.70710678118654752f;
    float2 ctw0;
    { float s, c; __sincosf(TWO_PI * (float)l * (1.0f/512.0f), &s, &c);
      ctw0 = make_float2(c, s); }
    float2 w1;
    { float s, c; __sincosf(TWO_PI * (float)l * (1.0f/256.0f), &s, &c);
      w1 = make_float2(c, s); }
    float2 b1;
    { float s, c; __sincosf(TWO_PI * (float)(l & 15) * (1.0f/64.0f), &s, &c);
      b1 = make_float2(c, s); }
    float2 q1;
    { float s, c; __sincosf(TWO_PI * (float)(l & 3) * (1.0f/16.0f), &s, &c);
      q1 = make_float2(c, s); }
    // Window weights for samples 2l+128o (x) / 2l+1+128o (y); Hann identity
    // ww[2]=2S-ww[0], ww[3]=2S-ww[1] keeps only o=0,1 persistent.
    const float S2 = 1.3020833333e-3f;    // 2 * 0.5/768
    float wwx0, wwx1, wwy0, wwy1;
    {
        const float S = 6.5104166667e-4f;   // 0.5/768
        float sx, cx; __sincosf(TWO_PI * (float)(2*l) * (1.0f/512.0f), &sx, &cx);
        wwx0 = S*(1.0f-cx); wwx1 = S*(1.0f+sx);
        float sy, cy; __sincosf(TWO_PI * (float)(2*l+1) * (1.0f/512.0f), &sy, &cy);
        wwy0 = S*(1.0f-cy); wwy1 = S*(1.0f+sy);
    }
    // Transpose layouts (float4 index; conflict profile known-minor:
    // ~2.5M conflict cycles ~5% -- later-round candidate).
    const int a1w = l;                                        // + 64*t0
    const int a1r = (l & 15) + 64 * (l >> 4);                 // + 16*q
    const int a2w = (l & 15) + 20 * (l >> 4);                 // + 80*t1
    const int a2r = (l & 3) + 20 * ((l >> 2) & 3) + 80 * (l >> 4);   // + 4*r
    const int a3w = ((l >> 2) & 3) + 4 * (l >> 4) + 20 * (l & 3);    // + 80*t2
    const int a3r = (l & 3) + 4 * ((l >> 2) & 3) + 80 * (l >> 4);    // + 20*k0

    float accx[4], accy[4];
    #pragma unroll
    for (int o = 0; o < 4; ++o) { accx[o] = 0.0f; accy[o] = 0.0f; }

    // Raw prefetch registers for the next PAIR of frames.
    float dra[4], dia[4], mra[4], mia[4];
    float drb[4], dib[4], mrb[4], mib[4];

    auto issue_loads = [&](int fq) {           // frames fq (a) and fq+1 (b)
        const int fca = min(max(fq,     0), NFRAMES - 1);
        const int fcb = min(max(fq + 1, 0), NFRAMES - 1);
        const float* __restrict__ rba = reb + (size_t)fca * NBINS;
        const float* __restrict__ iba = imb + (size_t)fca * NBINS;
        const float* __restrict__ rbb = reb + (size_t)fcb * NBINS;
        const float* __restrict__ ibb = imb + (size_t)fcb * NBINS;
        #pragma unroll
        for (int j = 0; j < 4; ++j) {
            const int k = l + 64*j, km = 256 - k;
            dra[j] = rba[k];  dia[j] = iba[k];
            mra[j] = rba[km]; mia[j] = iba[km];
            drb[j] = rbb[k];  dib[j] = ibb[k];
            mrb[j] = rbb[km]; mib[j] = ibb[km];
        }
    };

    // Stage-1 math for one frame: pack + dft4 + w-twiddles -> A[4].
    auto s1frame = [&](const float* dr_, const float* di_,
                       const float* mr_, const float* mi_,
                       float2 w2t, float2 w3t, float2* A) {
        float2 Cv[4];
        float cc = ctw0.x, ss = ctw0.y;   // walking twiddle, pi/4 per j-step
        #pragma unroll
        for (int j = 0; j < 4; ++j) {
            float ydr = dr_[j], ydi = di_[j], ymr = mr_[j], ymi = mi_[j];
            if (j == 0) {                       // k==0: Im of DC & Nyquist ignored
                const bool z = (l == 0);
                ydi = z ? 0.0f : ydi;
                ymi = z ? 0.0f : ymi;
            }
            const float er  = ydr + ymr, ei  = ydi - ymi;
            const float fr2 = ydr - ymr, fi2 = ydi + ymi;
            const float gr = cc*fr2 - ss*fi2;
            const float gi = cc*fi2 + ss*fr2;
            Cv[j] = make_float2(er - gi, ei + gr);
            const float cn = (cc - ss) * RQ, sn = (ss + cc) * RQ;  // rotate pi/4
            cc = cn; ss = sn;
        }
        dft4(Cv, A);
        A[1] = cmul(A[1], w1); A[2] = cmul(A[2], w2t); A[3] = cmul(A[3], w3t);
    };

    auto stage1 = [&](float4* __restrict__ P) {
        const float2 w2t = cmul(w1, w1);       // transient remat (reg trim)
        const float2 w3t = cmul(w2t, w1);
        float2 Aa[4], Ab[4];
        s1frame(dra, dia, mra, mia, w2t, w3t, Aa);
        s1frame(drb, dib, mrb, mib, w2t, w3t, Ab);
        #pragma unroll
        for (int j = 0; j < 4; ++j)
            P[a1w + 64*j] = make_float4(Aa[j].x, Aa[j].y, Ab[j].x, Ab[j].y);
    };

    auto stages234 = [&](float4* __restrict__ P, int fa) {
        float2 Ga[4], Gb[4], Aa[4], Ab[4];
        // ---- stage 2 ----
        #pragma unroll
        for (int t = 0; t < 4; ++t) {
            const float4 g = P[a1r + 16*t];
            Ga[t] = make_float2(g.x, g.y); Gb[t] = make_float2(g.z, g.w);
        }
        dft4(Ga, Aa); dft4(Gb, Ab);
        {
            const float2 b2t = cmul(b1, b1);   // transient remat (reg trim)
            const float2 b3t = cmul(b2t, b1);
            Aa[1]=cmul(Aa[1],b1); Aa[2]=cmul(Aa[2],b2t); Aa[3]=cmul(Aa[3],b3t);
            Ab[1]=cmul(Ab[1],b1); Ab[2]=cmul(Ab[2],b2t); Ab[3]=cmul(Ab[3],b3t);
        }
        #pragma unroll
        for (int t = 0; t < 4; ++t)
            P[a2w + 80*t] = make_float4(Aa[t].x, Aa[t].y, Ab[t].x, Ab[t].y);
        // ---- stage 3 ----
        #pragma unroll
        for (int t = 0; t < 4; ++t) {
            const float4 g = P[a2r + 4*t];
            Ga[t] = make_float2(g.x, g.y); Gb[t] = make_float2(g.z, g.w);
        }
        dft4(Ga, Aa); dft4(Gb, Ab);
        {
            const float2 q2t = cmul(q1, q1);   // transient remat (reg trim)
            const float2 q3t = cmul(q2t, q1);
            Aa[1]=cmul(Aa[1],q1); Aa[2]=cmul(Aa[2],q2t); Aa[3]=cmul(Aa[3],q3t);
            Ab[1]=cmul(Ab[1],q1); Ab[2]=cmul(Ab[2],q2t); Ab[3]=cmul(Ab[3],q3t);
        }
        #pragma unroll
        for (int t = 0; t < 4; ++t)
            P[a3w + 80*t] = make_float4(Aa[t].x, Aa[t].y, Ab[t].x, Ab[t].y);
        // ---- stage 4 ----
        #pragma unroll
        for (int t = 0; t < 4; ++t) {
            const float4 g = P[a3r + 20*t];
            Ga[t] = make_float2(g.x, g.y); Gb[t] = make_float2(g.z, g.w);
        }
        dft4(Ga, Aa); dft4(Gb, Ab);
        // ---- OLA: frame fa first (chunk fa must NOT see frame fb), then fb ----
        const int fb = fa + 1;
        if (fa >= 0 && fa < NFRAMES) {          // wave-uniform gate
            accx[0] = fmaf(Aa[0].x, wwx0, accx[0]);
            accx[1] = fmaf(Aa[1].x, wwx1, accx[1]);
            accx[2] = fmaf(Aa[2].x, S2, fmaf(-Aa[2].x, wwx0, accx[2]));
            accx[3] = fmaf(Aa[3].x, S2, fmaf(-Aa[3].x, wwx1, accx[3]));
            accy[0] = fmaf(Aa[0].y, wwy0, accy[0]);
            accy[1] = fmaf(Aa[1].y, wwy1, accy[1]);
            accy[2] = fmaf(Aa[2].y, S2, fmaf(-Aa[2].y, wwy0, accy[2]));
            accy[3] = fmaf(Aa[3].y, S2, fmaf(-Aa[3].y, wwy1, accy[3]));
        }
        if (fa >= c0 && fa <= fend) {           // emit chunk fa (complete now)
            const int s0 = fa * HOP + 2*l;      // max 512382 < OUT_LEN
            outb[s0] = accx[0];
            const int s1 = s0 + 1;
            if (s1 < OUT_LEN) outb[s1] = accy[0];
        }
        #pragma unroll
        for (int o = 0; o < 3; ++o) { accx[o] = accx[o+1]; accy[o] = accy[o+1]; }
        accx[3] = 0.0f; accy[3] = 0.0f;
        if (fb >= 0 && fb < NFRAMES) {
            accx[0] = fmaf(Ab[0].x, wwx0, accx[0]);
            accx[1] = fmaf(Ab[1].x, wwx1, accx[1]);
            accx[2] = fmaf(Ab[2].x, S2, fmaf(-Ab[2].x, wwx0, accx[2]));
            accx[3] = fmaf(Ab[3].x, S2, fmaf(-Ab[3].x, wwx1, accx[3]));
            accy[0] = fmaf(Ab[0].y, wwy0, accy[0]);
            accy[1] = fmaf(Ab[1].y, wwy1, accy[1]);
            accy[2] = fmaf(Ab[2].y, S2, fmaf(-Ab[2].y, wwy0, accy[2]));
            accy[3] = fmaf(Ab[3].y, S2, fmaf(-Ab[3].y, wwy1, accy[3]));
        }
        if (fb >= c0 && fb <= fend) {
            const int s0 = fb * HOP + 2*l;
            outb[s0] = accx[0];
            const int s1 = s0 + 1;
            if (s1 < OUT_LEN) outb[s1] = accy[0];
        }
        #pragma unroll
        for (int o = 0; o < 3; ++o) { accx[o] = accx[o+1]; accy[o] = accy[o+1]; }
        accx[3] = 0.0f; accy[3] = 0.0f;
    };

    // ---- software-pipelined pair loop: NPAIRS pairs = frames c0-4 .. c0+CPR-1 ----
    // (frame c0-4 contributes only to chunks < c0: harmless 1-frame halo waste;
    //  frames > fend are load-clamped + acc/emit-gated.)
    const int base = c0 - 4;
    issue_loads(base);
    stage1(PA);
    #pragma unroll 1
    for (int p = 0; p < NPAIRS; p += 2) {
        issue_loads(base + 2*(p+1));   // in flight during stages234(pair p)
        stages234(PA, base + 2*p);
        stage1(PBp);                   // consumes pair p+1 loads
        if (p + 2 < NPAIRS) issue_loads(base + 2*(p+2));
        stages234(PBp, base + 2*(p+1));
        if (p + 2 < NPAIRS) stage1(PA);
    }
}

extern "C" void kernel_launch(void* const* d_in, const int* in_sizes, int n_in,
                              void* d_out, int out_size, void* d_ws, size_t ws_size,
                              hipStream_t stream) {
    (void)in_sizes; (void)n_in; (void)d_ws; (void)ws_size; (void)out_size;
    const float* re = (const float*)d_in[0];
    const float* im = (const float*)d_in[1];
    float* out = (float*)d_out;

    // 16 batches x 334 ranges = 5344 waves; 4 waves per 256-thread block.
    // 1336 blocks = 5.22/CU over 3-resident (85-VGPR band) -> 2 rounds, 87% util.
    const int nblocks = (NB * RPB) / 4;   // 1336
    istft_pk4_kernel<<<dim3(nblocks), dim3(256), 0, stream>>>(re, im, out);
}

// Round 6
// 164.855 us; speedup vs baseline: 1.1525x; 1.1160x over previous
//
#include <hip/hip_runtime.h>
#include <math.h>

#define HOP       128
#define NBINS     257
#define NFRAMES   4000
#define NB        16
#define OUT_LEN   512383          // (4000-1)*128 + 512 - 1
#define CPR       22              // chunks per range (per wave)
#define RPB       182             // ranges per batch = ceil(4003/22)
#define NCHUNK    4003            // output chunks of 128 (last has 127 samples)
#define NPAIRS    13              // frame-pairs per wave = (CPR+4)/2
#define PBF4      320             // per-wave LDS scratch (float4) per buffer

__device__ __forceinline__ float2 cmul(float2 a, float2 b) {
    return make_float2(a.x*b.x - a.y*b.y, a.x*b.y + a.y*b.x);
}

// Inverse-sign DFT4: y[t] = sum_j x[j] * i^(j*t)
__device__ __forceinline__ void dft4(const float2* x, float2* y) {
    const float s0r=x[0].x+x[2].x, s0i=x[0].y+x[2].y;
    const float d0r=x[0].x-x[2].x, d0i=x[0].y-x[2].y;
    const float s1r=x[1].x+x[3].x, s1i=x[1].y+x[3].y;
    const float d1r=x[1].x-x[3].x, d1i=x[1].y-x[3].y;
    y[0]=make_float2(s0r+s1r, s0i+s1i);
    y[2]=make_float2(s0r-s1r, s0i-s1i);
    y[1]=make_float2(d0r-d1i, d0i+d1r);   // d0 + i*d1
    y[3]=make_float2(d0r+d1i, d0i-d1r);   // d0 - i*d1
}

// Real-packed iSTFT, 2-frame-paired packed 256-pt inverse FFTs (.xy/.zw of
// float4 LDS slots, b128 transposes), register OLA, no barriers.
//
// OCCUPANCY MODEL (validated r0-r5): waves/EU = floor(256 / VGPR_Count);
//   launch_bounds(256,N) caps allocator at floor(256/N) VGPRs.
//     r1: cap32 -> spill catastrophe (293us)   r2: cap64 -> spill (160us)
//     r3: cap128 used 88 -> 2 waves/EU, 72.4us, zero spill
//     r5: cap85 used 84 BUT SPILLED ~6 regs (WRITE 32->49MB), 81us.
//   Lesson: demand must fit the cap with slack, not be squeezed into it.
//
// THIS ROUND: mirror loads eliminated. Y[256-k] for lane l is lane
// (64-l)&63's Y[k'] with k'=3-j (identity (64-l)+64(3-j)=256-l-64j);
// lane 0 fixup: m[j]=d[4-j], m[0]=bin 256 (Nyquist, loaded once/frame).
// Reconstructed via __shfl (ds_bpermute, conflict-free permutation) at
// stage-1.  -16 persistent prefetch VGPRs (+4 nyq) -> demand ~76-80 fits
// the (256,3)=85 cap with slack -> 3 waves/EU, zero spill.  Also halves
// global loads (32 -> 20 dwords/pair).
//
// CPR LEDGER: r3 CPR=8: 1.5x halo, 98% fill @2/EU cap.  r4 CPR=16: 2 ragged
// fills @8waves/CU cap -> regression.  r6 CPR=22: 2912 waves <= 3072 slots
// (12 waves/CU @ 3/EU) -> SINGLE co-resident fill, halo 26/22 = 1.18x.
__global__ __launch_bounds__(256, 3)
void istft_pk4_kernel(const float* __restrict__ re,
                      const float* __restrict__ im,
                      float* __restrict__ out)
{
    __shared__ float4 bufA[4][PBF4];   // 4 waves * 320 * 16 B = 20480 B
    __shared__ float4 bufB[4][PBF4];   // total 40960 B / block
    // LDS at 3 blocks/CU = 122880 B <= 163840 -- not binding.

    const int tid = threadIdx.x;
    const int wv  = tid >> 6;
    const int l   = tid & 63;
    float4* PA = bufA[wv];
    float4* PBp = bufB[wv];

    const int rid = blockIdx.x * 4 + wv;     // 0..2911 exact
    const int b   = rid / RPB;
    const int rr  = rid - b * RPB;
    const int c0  = rr * CPR;
    const int fend = min(c0 + CPR - 1, NCHUNK - 1);

    const float* __restrict__ reb = re + (size_t)b * NFRAMES * NBINS;
    const float* __restrict__ imb = im + (size_t)b * NFRAMES * NBINS;
    float* __restrict__ outb = out + (size_t)b * OUT_LEN;

    // ---- frame-invariant per-lane constants (persistent set minimal:
    //      ctw0, w1, b1, q1, ww*4; squares/cubes remat per use) ----
    const float TWO_PI = 6.2831853071795864f;
    const float RQ = 0.70710678118654752f;
    float2 ctw0;
    { float s, c; __sincosf(TWO_PI * (float)l * (1.0f/512.0f), &s, &c);
      ctw0 = make_float2(c, s); }
    float2 w1;
    { float s, c; __sincosf(TWO_PI * (float)l * (1.0f/256.0f), &s, &c);
      w1 = make_float2(c, s); }
    float2 b1;
    { float s, c; __sincosf(TWO_PI * (float)(l & 15) * (1.0f/64.0f), &s, &c);
      b1 = make_float2(c, s); }
    float2 q1;
    { float s, c; __sincosf(TWO_PI * (float)(l & 3) * (1.0f/16.0f), &s, &c);
      q1 = make_float2(c, s); }
    // Window weights for samples 2l+128o (x) / 2l+1+128o (y); Hann identity
    // ww[2]=2S-ww[0], ww[3]=2S-ww[1] keeps only o=0,1 persistent.
    const float S2 = 1.3020833333e-3f;    // 2 * 0.5/768
    float wwx0, wwx1, wwy0, wwy1;
    {
        const float S = 6.5104166667e-4f;   // 0.5/768
        float sx, cx; __sincosf(TWO_PI * (float)(2*l) * (1.0f/512.0f), &sx, &cx);
        wwx0 = S*(1.0f-cx); wwx1 = S*(1.0f+sx);
        float sy, cy; __sincosf(TWO_PI * (float)(2*l+1) * (1.0f/512.0f), &sy, &cy);
        wwy0 = S*(1.0f-cy); wwy1 = S*(1.0f+sy);
    }
    // Transpose layouts (float4 index; conflict profile known-minor ~5%).
    const int a1w = l;                                        // + 64*t0
    const int a1r = (l & 15) + 64 * (l >> 4);                 // + 16*q
    const int a2w = (l & 15) + 20 * (l >> 4);                 // + 80*t1
    const int a2r = (l & 3) + 20 * ((l >> 2) & 3) + 80 * (l >> 4);   // + 4*r
    const int a3w = ((l >> 2) & 3) + 4 * (l >> 4) + 20 * (l & 3);    // + 80*t2
    const int a3r = (l & 3) + 4 * ((l >> 2) & 3) + 80 * (l >> 4);    // + 20*k0
    const int revl = (64 - l) & 63;                           // mirror src lane

    float accx[4], accy[4];
    #pragma unroll
    for (int o = 0; o < 4; ++o) { accx[o] = 0.0f; accy[o] = 0.0f; }

    // Raw prefetch registers for the next PAIR of frames (k-side only;
    // mirrors reconstructed by shuffle at consumption).
    float dra[4], dia[4], drb[4], dib[4];
    float nyra, nyia, nyrb, nyib;

    auto issue_loads = [&](int fq) {           // frames fq (a) and fq+1 (b)
        const int fca = min(max(fq,     0), NFRAMES - 1);
        const int fcb = min(max(fq + 1, 0), NFRAMES - 1);
        const float* __restrict__ rba = reb + (size_t)fca * NBINS;
        const float* __restrict__ iba = imb + (size_t)fca * NBINS;
        const float* __restrict__ rbb = reb + (size_t)fcb * NBINS;
        const float* __restrict__ ibb = imb + (size_t)fcb * NBINS;
        #pragma unroll
        for (int j = 0; j < 4; ++j) {
            const int k = l + 64*j;
            dra[j] = rba[k]; dia[j] = iba[k];
            drb[j] = rbb[k]; dib[j] = ibb[k];
        }
        nyra = rba[256]; nyia = iba[256];      // Nyquist bin (uniform line)
        nyrb = rbb[256]; nyib = ibb[256];
    };

    // Stage-1 math for one frame: shuffle-mirror + pack + dft4 + w-twiddles.
    auto s1frame = [&](const float* dr_, const float* di_, float nyr, float nyi,
                       float2 w2t, float2 w3t, float2* A) {
        // Reconstruct Y[256-k]: lane-reversal shuffle of the k-side loads.
        float mr_[4], mi_[4];
        #pragma unroll
        for (int j = 0; j < 4; ++j) {
            float vr = __shfl(dr_[3-j], revl, 64);
            float vi = __shfl(di_[3-j], revl, 64);
            if (j == 0) {
                if (l == 0) { vr = nyr; vi = nyi; }
            } else {
                if (l == 0) { vr = dr_[4-j]; vi = di_[4-j]; }
            }
            mr_[j] = vr; mi_[j] = vi;
        }
        float2 Cv[4];
        float cc = ctw0.x, ss = ctw0.y;   // walking twiddle, pi/4 per j-step
        #pragma unroll
        for (int j = 0; j < 4; ++j) {
            float ydr = dr_[j], ydi = di_[j], ymr = mr_[j], ymi = mi_[j];
            if (j == 0) {                       // k==0: Im of DC & Nyquist ignored
                const bool z = (l == 0);
                ydi = z ? 0.0f : ydi;
                ymi = z ? 0.0f : ymi;
            }
            const float er  = ydr + ymr, ei  = ydi - ymi;
            const float fr2 = ydr - ymr, fi2 = ydi + ymi;
            const float gr = cc*fr2 - ss*fi2;
            const float gi = cc*fi2 + ss*fr2;
            Cv[j] = make_float2(er - gi, ei + gr);
            const float cn = (cc - ss) * RQ, sn = (ss + cc) * RQ;  // rotate pi/4
            cc = cn; ss = sn;
        }
        dft4(Cv, A);
        A[1] = cmul(A[1], w1); A[2] = cmul(A[2], w2t); A[3] = cmul(A[3], w3t);
    };

    auto stage1 = [&](float4* __restrict__ P) {
        const float2 w2t = cmul(w1, w1);       // transient remat (reg slack)
        const float2 w3t = cmul(w2t, w1);
        float2 Aa[4], Ab[4];
        s1frame(dra, dia, nyra, nyia, w2t, w3t, Aa);
        s1frame(drb, dib, nyrb, nyib, w2t, w3t, Ab);
        #pragma unroll
        for (int j = 0; j < 4; ++j)
            P[a1w + 64*j] = make_float4(Aa[j].x, Aa[j].y, Ab[j].x, Ab[j].y);
    };

    auto stages234 = [&](float4* __restrict__ P, int fa) {
        float2 Ga[4], Gb[4], Aa[4], Ab[4];
        // ---- stage 2 ----
        #pragma unroll
        for (int t = 0; t < 4; ++t) {
            const float4 g = P[a1r + 16*t];
            Ga[t] = make_float2(g.x, g.y); Gb[t] = make_float2(g.z, g.w);
        }
        dft4(Ga, Aa); dft4(Gb, Ab);
        {
            const float2 b2t = cmul(b1, b1);   // transient remat
            const float2 b3t = cmul(b2t, b1);
            Aa[1]=cmul(Aa[1],b1); Aa[2]=cmul(Aa[2],b2t); Aa[3]=cmul(Aa[3],b3t);
            Ab[1]=cmul(Ab[1],b1); Ab[2]=cmul(Ab[2],b2t); Ab[3]=cmul(Ab[3],b3t);
        }
        #pragma unroll
        for (int t = 0; t < 4; ++t)
            P[a2w + 80*t] = make_float4(Aa[t].x, Aa[t].y, Ab[t].x, Ab[t].y);
        // ---- stage 3 ----
        #pragma unroll
        for (int t = 0; t < 4; ++t) {
            const float4 g = P[a2r + 4*t];
            Ga[t] = make_float2(g.x, g.y); Gb[t] = make_float2(g.z, g.w);
        }
        dft4(Ga, Aa); dft4(Gb, Ab);
        {
            const float2 q2t = cmul(q1, q1);   // transient remat
            const float2 q3t = cmul(q2t, q1);
            Aa[1]=cmul(Aa[1],q1); Aa[2]=cmul(Aa[2],q2t); Aa[3]=cmul(Aa[3],q3t);
            Ab[1]=cmul(Ab[1],q1); Ab[2]=cmul(Ab[2],q2t); Ab[3]=cmul(Ab[3],q3t);
        }
        #pragma unroll
        for (int t = 0; t < 4; ++t)
            P[a3w + 80*t] = make_float4(Aa[t].x, Aa[t].y, Ab[t].x, Ab[t].y);
        // ---- stage 4 ----
        #pragma unroll
        for (int t = 0; t < 4; ++t) {
            const float4 g = P[a3r + 20*t];
            Ga[t] = make_float2(g.x, g.y); Gb[t] = make_float2(g.z, g.w);
        }
        dft4(Ga, Aa); dft4(Gb, Ab);
        // ---- OLA: frame fa first (chunk fa must NOT see frame fb), then fb ----
        const int fb = fa + 1;
        if (fa >= 0 && fa < NFRAMES) {          // wave-uniform gate
            accx[0] = fmaf(Aa[0].x, wwx0, accx[0]);
            accx[1] = fmaf(Aa[1].x, wwx1, accx[1]);
            accx[2] = fmaf(Aa[2].x, S2, fmaf(-Aa[2].x, wwx0, accx[2]));
            accx[3] = fmaf(Aa[3].x, S2, fmaf(-Aa[3].x, wwx1, accx[3]));
            accy[0] = fmaf(Aa[0].y, wwy0, accy[0]);
            accy[1] = fmaf(Aa[1].y, wwy1, accy[1]);
            accy[2] = fmaf(Aa[2].y, S2, fmaf(-Aa[2].y, wwy0, accy[2]));
            accy[3] = fmaf(Aa[3].y, S2, fmaf(-Aa[3].y, wwy1, accy[3]));
        }
        if (fa >= c0 && fa <= fend) {           // emit chunk fa (complete now)
            const int s0 = fa * HOP + 2*l;      // max 512382 < OUT_LEN
            outb[s0] = accx[0];
            const int s1 = s0 + 1;
            if (s1 < OUT_LEN) outb[s1] = accy[0];
        }
        #pragma unroll
        for (int o = 0; o < 3; ++o) { accx[o] = accx[o+1]; accy[o] = accy[o+1]; }
        accx[3] = 0.0f; accy[3] = 0.0f;
        if (fb >= 0 && fb < NFRAMES) {
            accx[0] = fmaf(Ab[0].x, wwx0, accx[0]);
            accx[1] = fmaf(Ab[1].x, wwx1, accx[1]);
            accx[2] = fmaf(Ab[2].x, S2, fmaf(-Ab[2].x, wwx0, accx[2]));
            accx[3] = fmaf(Ab[3].x, S2, fmaf(-Ab[3].x, wwx1, accx[3]));
            accy[0] = fmaf(Ab[0].y, wwy0, accy[0]);
            accy[1] = fmaf(Ab[1].y, wwy1, accy[1]);
            accy[2] = fmaf(Ab[2].y, S2, fmaf(-Ab[2].y, wwy0, accy[2]));
            accy[3] = fmaf(Ab[3].y, S2, fmaf(-Ab[3].y, wwy1, accy[3]));
        }
        if (fb >= c0 && fb <= fend) {
            const int s0 = fb * HOP + 2*l;
            outb[s0] = accx[0];
            const int s1 = s0 + 1;
            if (s1 < OUT_LEN) outb[s1] = accy[0];
        }
        #pragma unroll
        for (int o = 0; o < 3; ++o) { accx[o] = accx[o+1]; accy[o] = accy[o+1]; }
        accx[3] = 0.0f; accy[3] = 0.0f;
    };

    // ---- software-pipelined pair loop (uniform rotate; NPAIRS may be odd):
    //      frames base .. base+2*NPAIRS-1 = c0-4 .. c0+CPR-1 ----
    const int base = c0 - 4;
    issue_loads(base);
    stage1(PA);
    float4* cur = PA;
    float4* nxt = PBp;
    #pragma unroll 1
    for (int p = 0; p < NPAIRS; ++p) {
        if (p + 1 < NPAIRS) issue_loads(base + 2*(p+1)); // fly during stages234
        stages234(cur, base + 2*p);
        if (p + 1 < NPAIRS) stage1(nxt);                 // consumes p+1 loads
        float4* t = cur; cur = nxt; nxt = t;
    }
}

extern "C" void kernel_launch(void* const* d_in, const int* in_sizes, int n_in,
                              void* d_out, int out_size, void* d_ws, size_t ws_size,
                              hipStream_t stream) {
    (void)in_sizes; (void)n_in; (void)d_ws; (void)ws_size; (void)out_size;
    const float* re = (const float*)d_in[0];
    const float* im = (const float*)d_in[1];
    float* out = (float*)d_out;

    // 16 batches x 182 ranges = 2912 waves; 4 waves per 256-thread block.
    // 728 blocks <= 3072 wave slots at 3 waves/EU -> whole grid co-resident.
    const int nblocks = (NB * RPB) / 4;   // 728
    istft_pk4_kernel<<<dim3(nblocks), dim3(256), 0, stream>>>(re, im, out);
}